// Round 2
// baseline (2345.445 us; speedup 1.0000x reference)
//
#include <hip/hip_runtime.h>
#include <math.h>

#define T_LEN 1024
#define D_MODEL 1024
#define NKV 4
#define REP 4
#define DH 64
#define NB 63
#define TOPN 8

// concatenated projection layout (row stride LDIM, per-t)
#define LDIM 1584
#define KCMP_OFF 48
#define VCMP_OFF 304
#define KSLC_OFF 560
#define VSLC_OFF 816
#define KWIN_OFF 1072
#define VWIN_OFF 1328

typedef __attribute__((ext_vector_type(8))) short bf16x8;
typedef __attribute__((ext_vector_type(4))) float f32x4;

__device__ __forceinline__ float gelu_exact(float x) {
    return 0.5f * x * (1.0f + erff(x * 0.70710678118654752f));
}
__device__ __forceinline__ float sigmoidf(float x) {
    return 1.0f / (1.0f + expf(-x));
}
__device__ __forceinline__ unsigned short f2bf(float f) {
    union { float f; unsigned int u; } v; v.f = f;
    unsigned int u = v.u;
    unsigned int r = (u + 0x7FFFu + ((u >> 16) & 1u)) >> 16;  // RNE
    return (unsigned short)r;
}

// ---------------------------------------------------------------------------
// bf16 MFMA GEMM: proj[1024,1584] = x[1024,1024] @ Wcat[1584,1024]^T (+gate_b
// on cols<48). 64x64 tile, BK=32, 4 waves each own 16 rows x 64 cols.
// Weight row pointer resolved per staged row (concatenation is virtual).
// ---------------------------------------------------------------------------
__global__ __launch_bounds__(256) void proj_gemm(
    const float* __restrict__ x,
    const float* __restrict__ gate_w, const float* __restrict__ gate_b,
    const float* __restrict__ wk_cmp, const float* __restrict__ wv_cmp,
    const float* __restrict__ wk_slc, const float* __restrict__ wv_slc,
    const float* __restrict__ wk_win, const float* __restrict__ wv_win,
    float* __restrict__ proj)
{
    __shared__ unsigned short As[64][40];   // 80B rows -> 16B-aligned frag reads
    __shared__ unsigned short Bs[64][40];
    const int tid = threadIdx.x;
    const int lane = tid & 63;
    const int w = tid >> 6;
    const int n0 = blockIdx.x * 64;
    const int m0 = blockIdx.y * 64;

    const int srow = tid >> 2;   // 0..63
    const int sseg = tid & 3;    // 0..3, 8 elements each
    const float* ga = x + (m0 + srow) * D_MODEL + sseg * 8;
    const float* gb;
    {
        int nn = n0 + srow;
        if (nn < 48) gb = gate_w + nn * D_MODEL;
        else { nn -= 48;
        if (nn < 256) gb = wk_cmp + nn * D_MODEL;
        else { nn -= 256;
        if (nn < 256) gb = wv_cmp + nn * D_MODEL;
        else { nn -= 256;
        if (nn < 256) gb = wk_slc + nn * D_MODEL;
        else { nn -= 256;
        if (nn < 256) gb = wv_slc + nn * D_MODEL;
        else { nn -= 256;
        if (nn < 256) gb = wk_win + nn * D_MODEL;
        else { nn -= 256;
        if (nn < 256) gb = wv_win + nn * D_MODEL;
        else gb = gate_w; }}}}}}   // rows >=1584: dummy, masked at store
        gb += sseg * 8;
    }

    f32x4 acc[4] = {};
    const int arow = (w << 4) + (lane & 15);
    const int kk8  = (lane >> 4) * 8;

    for (int k0 = 0; k0 < D_MODEL; k0 += 32) {
        float4 a0 = *(const float4*)(ga + k0);
        float4 a1 = *(const float4*)(ga + k0 + 4);
        float4 b0 = *(const float4*)(gb + k0);
        float4 b1 = *(const float4*)(gb + k0 + 4);
        bf16x8 ap, bp;
        ap[0]=(short)f2bf(a0.x); ap[1]=(short)f2bf(a0.y); ap[2]=(short)f2bf(a0.z); ap[3]=(short)f2bf(a0.w);
        ap[4]=(short)f2bf(a1.x); ap[5]=(short)f2bf(a1.y); ap[6]=(short)f2bf(a1.z); ap[7]=(short)f2bf(a1.w);
        bp[0]=(short)f2bf(b0.x); bp[1]=(short)f2bf(b0.y); bp[2]=(short)f2bf(b0.z); bp[3]=(short)f2bf(b0.w);
        bp[4]=(short)f2bf(b1.x); bp[5]=(short)f2bf(b1.y); bp[6]=(short)f2bf(b1.z); bp[7]=(short)f2bf(b1.w);
        __syncthreads();
        *(bf16x8*)&As[srow][sseg * 8] = ap;
        *(bf16x8*)&Bs[srow][sseg * 8] = bp;
        __syncthreads();
        bf16x8 af = *(bf16x8*)&As[arow][kk8];
        #pragma unroll
        for (int j = 0; j < 4; ++j) {
            bf16x8 bfr = *(bf16x8*)&Bs[j * 16 + (lane & 15)][kk8];
            acc[j] = __builtin_amdgcn_mfma_f32_16x16x32_bf16(af, bfr, acc[j], 0, 0, 0);
        }
    }

    // C/D layout: col = lane&15, row = (lane>>4)*4 + reg  [m89-verified]
    #pragma unroll
    for (int j = 0; j < 4; ++j) {
        int col = n0 + j * 16 + (lane & 15);
        if (col >= LDIM) continue;
        float badd = (col < 48) ? gate_b[col] : 0.0f;
        int rbase = m0 + (w << 4) + (lane >> 4) * 4;
        #pragma unroll
        for (int rg = 0; rg < 4; ++rg)
            proj[(rbase + rg) * LDIM + col] = acc[j][rg] + badd;
    }
}

// ---------------------------------------------------------------------------
// f32 GEMM for k_cmp only (selection-critical path stays at f32 precision).
// Overwrites proj columns [48,304). 64x64 tile, BK=32, k-major LDS (+68 pad)
// for float4 fragment reads. Grid (4,16).
// ---------------------------------------------------------------------------
__global__ __launch_bounds__(256) void gemm_kcmp_f32(
    const float* __restrict__ A, const float* __restrict__ B,
    float* __restrict__ proj)
{
    __shared__ float As[32][68];
    __shared__ float Bs[32][68];
    const int tid = threadIdx.x;
    const int tx = tid & 15, ty = tid >> 4;
    const int n0 = blockIdx.x * 64, m0 = blockIdx.y * 64;
    const int srow = tid >> 2, sseg = tid & 3;
    const float* ga = A + (m0 + srow) * D_MODEL + sseg * 8;
    const float* gb = B + (n0 + srow) * D_MODEL + sseg * 8;

    float acc[4][4] = {};
    for (int k0 = 0; k0 < D_MODEL; k0 += 32) {
        float4 a0 = *(const float4*)(ga + k0);
        float4 a1 = *(const float4*)(ga + k0 + 4);
        float4 b0 = *(const float4*)(gb + k0);
        float4 b1 = *(const float4*)(gb + k0 + 4);
        __syncthreads();
        As[sseg*8+0][srow]=a0.x; As[sseg*8+1][srow]=a0.y; As[sseg*8+2][srow]=a0.z; As[sseg*8+3][srow]=a0.w;
        As[sseg*8+4][srow]=a1.x; As[sseg*8+5][srow]=a1.y; As[sseg*8+6][srow]=a1.z; As[sseg*8+7][srow]=a1.w;
        Bs[sseg*8+0][srow]=b0.x; Bs[sseg*8+1][srow]=b0.y; Bs[sseg*8+2][srow]=b0.z; Bs[sseg*8+3][srow]=b0.w;
        Bs[sseg*8+4][srow]=b1.x; Bs[sseg*8+5][srow]=b1.y; Bs[sseg*8+6][srow]=b1.z; Bs[sseg*8+7][srow]=b1.w;
        __syncthreads();
        #pragma unroll
        for (int kk = 0; kk < 32; ++kk) {
            float4 a4 = *(const float4*)&As[kk][ty * 4];
            float4 b4 = *(const float4*)&Bs[kk][tx * 4];
            acc[0][0] += a4.x*b4.x; acc[0][1] += a4.x*b4.y; acc[0][2] += a4.x*b4.z; acc[0][3] += a4.x*b4.w;
            acc[1][0] += a4.y*b4.x; acc[1][1] += a4.y*b4.y; acc[1][2] += a4.y*b4.z; acc[1][3] += a4.y*b4.w;
            acc[2][0] += a4.z*b4.x; acc[2][1] += a4.z*b4.y; acc[2][2] += a4.z*b4.z; acc[2][3] += a4.z*b4.w;
            acc[3][0] += a4.w*b4.x; acc[3][1] += a4.w*b4.y; acc[3][2] += a4.w*b4.z; acc[3][3] += a4.w*b4.w;
        }
    }
    #pragma unroll
    for (int i = 0; i < 4; ++i) {
        int m = m0 + ty * 4 + i;
        #pragma unroll
        for (int j = 0; j < 4; ++j) {
            int n = n0 + tx * 4 + j;
            proj[m * LDIM + KCMP_OFF + n] = acc[i][j];
        }
    }
}

// ---------------------------------------------------------------------------
// Block summaries from proj columns (k: 48.., v: 304..). grid (63,4,2)
// ---------------------------------------------------------------------------
__global__ __launch_bounds__(256) void nsa_summarize(
    const float* __restrict__ proj, const float* __restrict__ block_pos,
    const float* __restrict__ ck1_w, const float* __restrict__ ck1_b,
    const float* __restrict__ ck2_w, const float* __restrict__ ck2_b,
    const float* __restrict__ cv1_w, const float* __restrict__ cv1_b,
    const float* __restrict__ cv2_w, const float* __restrict__ cv2_b,
    float* __restrict__ ksum, float* __restrict__ vsum)
{
    const int n = blockIdx.x, k = blockIdx.y, which = blockIdx.z;
    const int off  = which ? VCMP_OFF : KCMP_OFF;
    const float* w1 = which ? cv1_w : ck1_w;
    const float* b1 = which ? cv1_b : ck1_b;
    const float* w2 = which ? cv2_w : ck2_w;
    const float* b2 = which ? cv2_b : ck2_b;
    float* dst      = which ? vsum  : ksum;

    __shared__ float flat[32 * DH];
    __shared__ float hidden[DH];
    const int tid = threadIdx.x;
    const int start = n * 16;

    for (int e = tid; e < 512; e += 256) {   // 512 float4s
        int p = e >> 4, d4 = e & 15;
        float4 s = *(const float4*)(proj + (start + p) * LDIM + off + k * DH + d4 * 4);
        float4 bp = *(const float4*)(block_pos + p * DH + d4 * 4);
        float4 r; r.x = s.x + bp.x; r.y = s.y + bp.y; r.z = s.z + bp.z; r.w = s.w + bp.w;
        *(float4*)&flat[p * DH + d4 * 4] = r;
    }
    __syncthreads();
    {
        int h = tid >> 2, part = tid & 3;
        const float* wr = w1 + h * 2048 + part * 512;
        const float* fl = flat + part * 512;
        float s = 0.0f;
        for (int j = 0; j < 512; j += 4) {
            float4 a = *(const float4*)(fl + j);
            float4 b = *(const float4*)(wr + j);
            s += a.x * b.x + a.y * b.y + a.z * b.z + a.w * b.w;
        }
        s += __shfl_xor(s, 1);
        s += __shfl_xor(s, 2);
        if (part == 0) hidden[h] = gelu_exact(s + b1[h]);
    }
    __syncthreads();
    {
        int dh = tid >> 2, part = tid & 3;
        const float* wr = w2 + dh * 64 + part * 16;
        float s = 0.0f;
        #pragma unroll
        for (int hh = 0; hh < 16; ++hh) s += hidden[part * 16 + hh] * wr[hh];
        s += __shfl_xor(s, 1);
        s += __shfl_xor(s, 2);
        if (part == 0) dst[(n * NKV + k) * DH + dh] = s + b2[dh];
    }
}

// ---------------------------------------------------------------------------
// Fused attention: one workgroup per (t, kv head); wave r = GQA rep r.
// q in VGPRs; all K/V staged via conflict-free float2 LDS (+66 row pad).
// ---------------------------------------------------------------------------
__global__ __launch_bounds__(256) void nsa_fused(
    const float* __restrict__ q, const float* __restrict__ proj,
    const float* __restrict__ ksum, const float* __restrict__ vsum,
    float* __restrict__ out)
{
    const int t = blockIdx.x, k = blockIdx.y;
    const int tid = threadIdx.x, lane = tid & 63, r = tid >> 6;

    __shared__ float chunk[64][66];
    __shared__ float sc_s[REP][256];
    __shared__ float p_cmp_s[REP][64];
    __shared__ int   sel_s[TOPN];

    // ---- q into registers (wave-uniform values, broadcast loads) ----
    float qv[64];
    const float* qrow = q + ((r * NKV + k) * T_LEN + t) * DH;
    #pragma unroll
    for (int i = 0; i < 16; ++i) {
        float4 v = *(const float4*)(qrow + i * 4);
        qv[i*4] = v.x; qv[i*4+1] = v.y; qv[i*4+2] = v.z; qv[i*4+3] = v.w;
    }

    // ---- compressed branch: stage ksum, scores, softmax ----
    for (int e = tid; e < 64 * 32; e += 256) {
        int p = e >> 5, d2 = e & 31;
        int nn = (p < NB) ? p : NB - 1;
        *(float2*)&chunk[p][d2 * 2] = *(const float2*)(ksum + (nn * NKV + k) * DH + d2 * 2);
    }
    __syncthreads();
    float s = -1e30f;
    if (lane < NB && (lane * 16 + 31) <= t) {
        float a = 0.0f;
        #pragma unroll
        for (int d = 0; d < 64; ++d) a += qv[d] * chunk[lane][d];
        s = a * 0.125f;
    }
    float m = s;
    for (int off = 32; off; off >>= 1) m = fmaxf(m, __shfl_xor(m, off));
    float ex = (lane < NB) ? expf(s - m) : 0.0f;
    float sum = ex;
    for (int off = 32; off; off >>= 1) sum += __shfl_xor(sum, off);
    p_cmp_s[r][lane] = ex / sum;   // lane 63 -> 0
    __syncthreads();

    // ---- top-8 (wave 0), stable tie-break on lower index ----
    if (r == 0) {
        float imp = (lane < NB)
            ? (p_cmp_s[0][lane] + p_cmp_s[1][lane] + p_cmp_s[2][lane] + p_cmp_s[3][lane])
            : -1e30f;
        for (int it = 0; it < TOPN; ++it) {
            float v = imp; int i = lane;
            for (int off = 32; off; off >>= 1) {
                float ov = __shfl_xor(v, off);
                int   oi = __shfl_xor(i, off);
                if (ov > v || (ov == v && oi < i)) { v = ov; i = oi; }
            }
            if (lane == 0) sel_s[it] = i;
            if (lane == i) imp = -1e30f;
        }
    }
    __syncthreads();

    // ---- out_cmp: stage vsum, weighted sum ----
    for (int e = tid; e < 64 * 32; e += 256) {
        int p = e >> 5, d2 = e & 31;
        int nn = (p < NB) ? p : NB - 1;
        *(float2*)&chunk[p][d2 * 2] = *(const float2*)(vsum + (nn * NKV + k) * DH + d2 * 2);
    }
    __syncthreads();
    float ocmp = 0.0f;
    if (t >= 31) {
        for (int p0 = 0; p0 < 64; p0 += 4) {   // entry 63 has p=0
            float4 pv = *(const float4*)&p_cmp_s[r][p0];
            ocmp += pv.x * chunk[p0][lane] + pv.y * chunk[p0+1][lane]
                  + pv.z * chunk[p0+2][lane] + pv.w * chunk[p0+3][lane];
        }
    }

    // ---- selected branch ----
    float oslc = 0.0f;
    for (int c = 0; c < 4; ++c) {
        __syncthreads();
        for (int e = tid; e < 64 * 32; e += 256) {
            int pidx = e >> 5, d2 = e & 31;
            int j = c * 64 + pidx;
            int pos = sel_s[j >> 5] * 16 + (j & 31);
            *(float2*)&chunk[pidx][d2 * 2] =
                *(const float2*)(proj + pos * LDIM + KSLC_OFF + k * DH + d2 * 2);
        }
        __syncthreads();
        int j = c * 64 + lane;
        int pos = sel_s[j >> 5] * 16 + (j & 31);
        float a = 0.0f;
        #pragma unroll
        for (int d = 0; d < 64; ++d) a += qv[d] * chunk[lane][d];
        sc_s[r][j] = (pos <= t) ? a * 0.125f : -1e30f;
    }
    __syncthreads();
    {
        float v0 = sc_s[r][lane],       v1 = sc_s[r][64 + lane];
        float v2 = sc_s[r][128 + lane], v3 = sc_s[r][192 + lane];
        float mx = fmaxf(fmaxf(v0, v1), fmaxf(v2, v3));
        for (int off = 32; off; off >>= 1) mx = fmaxf(mx, __shfl_xor(mx, off));
        float e0 = expf(v0 - mx), e1 = expf(v1 - mx), e2 = expf(v2 - mx), e3 = expf(v3 - mx);
        float sm = e0 + e1 + e2 + e3;
        for (int off = 32; off; off >>= 1) sm += __shfl_xor(sm, off);
        float inv = 1.0f / sm;
        sc_s[r][lane] = e0 * inv;       sc_s[r][64 + lane] = e1 * inv;
        sc_s[r][128 + lane] = e2 * inv; sc_s[r][192 + lane] = e3 * inv;
    }
    for (int c = 0; c < 4; ++c) {
        __syncthreads();
        for (int e = tid; e < 64 * 32; e += 256) {
            int pidx = e >> 5, d2 = e & 31;
            int j = c * 64 + pidx;
            int pos = sel_s[j >> 5] * 16 + (j & 31);
            *(float2*)&chunk[pidx][d2 * 2] =
                *(const float2*)(proj + pos * LDIM + VSLC_OFF + k * DH + d2 * 2);
        }
        __syncthreads();
        for (int p0 = 0; p0 < 64; p0 += 4) {
            float4 sv = *(const float4*)&sc_s[r][c * 64 + p0];
            oslc += sv.x * chunk[p0][lane] + sv.y * chunk[p0+1][lane]
                  + sv.z * chunk[p0+2][lane] + sv.w * chunk[p0+3][lane];
        }
    }

    // ---- sliding-window branch ----
    float owin = 0.0f;
    const int j0 = (t >= 255) ? (t - 255) : 0;
    const int W = t - j0 + 1;
    for (int c = 0; c < 4; ++c) {
        __syncthreads();
        for (int e = tid; e < 64 * 32; e += 256) {
            int pidx = e >> 5, d2 = e & 31;
            int pos = j0 + c * 64 + pidx;
            *(float2*)&chunk[pidx][d2 * 2] =
                *(const float2*)(proj + pos * LDIM + KWIN_OFF + k * DH + d2 * 2);
        }
        __syncthreads();
        int jj = c * 64 + lane;
        float a = 0.0f;
        #pragma unroll
        for (int d = 0; d < 64; ++d) a += qv[d] * chunk[lane][d];
        sc_s[r][jj] = (jj < W) ? a * 0.125f : -1e30f;
    }
    __syncthreads();
    {
        float v0 = sc_s[r][lane],       v1 = sc_s[r][64 + lane];
        float v2 = sc_s[r][128 + lane], v3 = sc_s[r][192 + lane];
        float mx = fmaxf(fmaxf(v0, v1), fmaxf(v2, v3));
        for (int off = 32; off; off >>= 1) mx = fmaxf(mx, __shfl_xor(mx, off));
        float e0 = expf(v0 - mx), e1 = expf(v1 - mx), e2 = expf(v2 - mx), e3 = expf(v3 - mx);
        float sm = e0 + e1 + e2 + e3;
        for (int off = 32; off; off >>= 1) sm += __shfl_xor(sm, off);
        float inv = 1.0f / sm;
        sc_s[r][lane] = e0 * inv;       sc_s[r][64 + lane] = e1 * inv;
        sc_s[r][128 + lane] = e2 * inv; sc_s[r][192 + lane] = e3 * inv;
    }
    for (int c = 0; c < 4; ++c) {
        __syncthreads();
        for (int e = tid; e < 64 * 32; e += 256) {
            int pidx = e >> 5, d2 = e & 31;
            int pos = j0 + c * 64 + pidx;
            *(float2*)&chunk[pidx][d2 * 2] =
                *(const float2*)(proj + pos * LDIM + VWIN_OFF + k * DH + d2 * 2);
        }
        __syncthreads();
        for (int p0 = 0; p0 < 64; p0 += 4) {
            float4 sv = *(const float4*)&sc_s[r][c * 64 + p0];
            owin += sv.x * chunk[p0][lane] + sv.y * chunk[p0+1][lane]
                  + sv.z * chunk[p0+2][lane] + sv.w * chunk[p0+3][lane];
        }
    }

    // ---- gates + write ----
    const int hq = r * NKV + k;
    float g0 = sigmoidf(proj[t * LDIM + hq * 3 + 0]);
    float g1 = sigmoidf(proj[t * LDIM + hq * 3 + 1]);
    float g2 = sigmoidf(proj[t * LDIM + hq * 3 + 2]);
    out[(hq * T_LEN + t) * DH + lane] = g0 * ocmp + g1 * oslc + g2 * owin;
}

extern "C" void kernel_launch(void* const* d_in, const int* in_sizes, int n_in,
                              void* d_out, int out_size, void* d_ws, size_t ws_size,
                              hipStream_t stream) {
    const float* x         = (const float*)d_in[0];
    const float* q         = (const float*)d_in[1];
    const float* gate_w    = (const float*)d_in[2];
    const float* gate_b    = (const float*)d_in[3];
    const float* wk_cmp    = (const float*)d_in[4];
    const float* wv_cmp    = (const float*)d_in[5];
    const float* wk_slc    = (const float*)d_in[6];
    const float* wv_slc    = (const float*)d_in[7];
    const float* wk_win    = (const float*)d_in[8];
    const float* wv_win    = (const float*)d_in[9];
    const float* block_pos = (const float*)d_in[10];
    const float* ck1_w     = (const float*)d_in[11];
    const float* ck1_b     = (const float*)d_in[12];
    const float* ck2_w     = (const float*)d_in[13];
    const float* ck2_b     = (const float*)d_in[14];
    const float* cv1_w     = (const float*)d_in[15];
    const float* cv1_b     = (const float*)d_in[16];
    const float* cv2_w     = (const float*)d_in[17];
    const float* cv2_b     = (const float*)d_in[18];
    float* out = (float*)d_out;

    float* ws   = (float*)d_ws;
    float* proj = ws;                         // 1024*1584 f32
    float* ksum = proj + T_LEN * LDIM;        // 63*4*64
    float* vsum = ksum + NB * NKV * DH;

    dim3 blk(256);
    // all projections (bf16 MFMA), incl. gates; k_cmp cols overwritten next
    proj_gemm<<<dim3(25, 16), blk, 0, stream>>>(
        x, gate_w, gate_b, wk_cmp, wv_cmp, wk_slc, wv_slc, wk_win, wv_win, proj);
    // selection-critical k_cmp in f32 (overwrites cols 48..303; stream-ordered)
    gemm_kcmp_f32<<<dim3(4, 16), blk, 0, stream>>>(x, wk_cmp, proj);
    // block summaries
    nsa_summarize<<<dim3(NB, NKV, 2), blk, 0, stream>>>(
        proj, block_pos, ck1_w, ck1_b, ck2_w, ck2_b, cv1_w, cv1_b, cv2_w, cv2_b,
        ksum, vsum);
    // fused attention + gating
    nsa_fused<<<dim3(T_LEN, NKV), blk, 0, stream>>>(q, proj, ksum, vsum, out);
}